// Round 5
// baseline (232.568 us; speedup 1.0000x reference)
//
#include <hip/hip_runtime.h>

#define B_ 16
#define C_ 256
#define L_ 2048

typedef __attribute__((ext_vector_type(8))) short short8;
typedef __attribute__((ext_vector_type(4))) float float4v;

__device__ inline float4v mfma16(short8 a, short8 b, float4v c) {
  return __builtin_amdgcn_mfma_f32_16x16x32_bf16(a, b, c, 0, 0, 0);
}

__device__ inline ushort f2bf(float x) {
  union { float f; unsigned u; } v; v.f = x;
  unsigned r = (v.u + 0x7fffu + ((v.u >> 16) & 1u)) >> 16;
  return (ushort)r;
}

// async global->LDS, 16B/lane, LDS dest = wave-uniform base + lane*16
__device__ inline void dma16(const ushort* g, void* l) {
  __builtin_amdgcn_global_load_lds(
      (const __attribute__((address_space(1))) unsigned int*)(g),
      (__attribute__((address_space(3))) unsigned int*)(l), 16, 0, 0);
}

// barrier that drains everything (use when DMA'd data is consumed next)
#define BAR_FULL() asm volatile("s_waitcnt vmcnt(0) lgkmcnt(0)\ns_barrier" ::: "memory")
// barrier that drains only LDS ops (keeps DMA in flight)
#define BAR_LGKM() asm volatile("s_waitcnt lgkmcnt(0)\ns_barrier" ::: "memory")

// ---------------- convert: y fp32 -> yb [B,C,L] bf16 and ytb [B,L,C] bf16 ---
__global__ __launch_bounds__(256) void cvt_kernel(const float* __restrict__ y,
                                                  ushort* __restrict__ yb,
                                                  ushort* __restrict__ ytb) {
  __shared__ float tile[32][33];
  int b = blockIdx.z, ct = blockIdx.y, lt = blockIdx.x;
  int tx = threadIdx.x & 31, ty = threadIdx.x >> 5;
  size_t base = ((size_t)b * C_ + (size_t)ct * 32) * L_ + (size_t)lt * 32;
#pragma unroll
  for (int i = 0; i < 4; ++i) {
    int r = ty + i * 8;
    float v = y[base + (size_t)r * L_ + tx];
    tile[r][tx] = v;
    yb[base + (size_t)r * L_ + tx] = f2bf(v);
  }
  __syncthreads();
  size_t tbase = ((size_t)b * L_ + (size_t)lt * 32) * C_ + (size_t)ct * 32;
#pragma unroll
  for (int i = 0; i < 4; ++i) {
    int r = ty + i * 8;
    ytb[tbase + (size_t)r * C_ + tx] = f2bf(tile[tx][r]);
  }
}

// ---------------- fused channel attention: out = alpha*y_c + gamma*y -------
// block: (b, 16 q-rows m0, L-half). Phase A: S=Y.Y^T rows via DMA-staged yb
// chunks; P kept in LDS. Phase B: PV over this block's L-half via DMA-staged
// ytb chunks; epilogue applies alpha*ginv and gamma*y.
__global__ __launch_bounds__(256) void chan_kernel(
    const ushort* __restrict__ yb, const ushort* __restrict__ ytb,
    const float* __restrict__ y, float* __restrict__ out,
    const float* __restrict__ alpha_p, const float* __restrict__ gamma_p) {
  const int blk = blockIdx.x;
  const int b = (blk & 7) + 8 * ((blk >> 3) & 1);
  const int rest = blk >> 4;
  const int m0 = (rest & 15) * 16;
  const int Lh = rest >> 4;  // 0 or 1: L-half for Phase B
  const int tid = threadIdx.x;
  const int w = tid >> 6, lane = tid & 63, quad = lane >> 4, l16 = lane & 15;
  const float scale = 0.022097086912079608f;  // 1/sqrt(2048)
  const float SHIFT = 45.0f;

  __shared__ __align__(16) unsigned char Tb[2][32768];
  __shared__ ushort Pl[16 * 264];  // stride 264 ush = 132 words -> 2-way banks
  __shared__ float wsum[4][16];
  __shared__ float ginvb[16];

  const ushort* Yb = yb + (size_t)b * C_ * L_;
  const ushort* Yt = ytb + (size_t)b * L_ * C_;
  const int chq = ((lane & 3) - ((lane >> 3) & 3)) & 3;
  const int sK = (quad + ((l16 >> 1) & 3)) & 3;
  const int frag_lane = l16 * 64 + sK * 16;

  // ---- Phase A: scores over K=2048, 64-L chunks double-buffered ----
  // A-chunk DMA pointers (gi = w*8+j : kk2 = gi>>4, chgrp = gi&15)
  const ushort* ap[8];
#pragma unroll
  for (int j = 0; j < 8; ++j) {
    int gi = w * 8 + j, kk2 = gi >> 4, chgrp = gi & 15;
    ap[j] = Yb + (size_t)chgrp * 16 * L_ + kk2 * 32 + (lane >> 2) * L_ + chq * 8;
  }
  // V-chunk DMA pointers (gi: pg = gi>>3, kk = gi&7), start at this L-half
  const ushort* vp[8];
#pragma unroll
  for (int j = 0; j < 8; ++j) {
    int gi = w * 8 + j, pg = gi >> 3, kk = gi & 7;
    vp[j] = Yt + (size_t)(Lh * 1024 + pg * 16 + (lane >> 2)) * C_ + kk * 32 + chq * 8;
  }

  // preload A chunk 0
#pragma unroll
  for (int j = 0; j < 8; ++j) {
    dma16(ap[j], (void*)(Tb[0] + (w * 8 + j) * 1024));
    ap[j] += 64;
  }

  float4v acc[4];
#pragma unroll
  for (int nt = 0; nt < 4; ++nt) acc[nt] = (float4v){0.f, 0.f, 0.f, 0.f};

  for (int c = 0; c < 32; ++c) {
    BAR_FULL();
    if (c < 31) {
      unsigned char* bp = Tb[(c + 1) & 1];
#pragma unroll
      for (int j = 0; j < 8; ++j) {
        dma16(ap[j], (void*)(bp + (w * 8 + j) * 1024));
        ap[j] += 64;
      }
    } else {
      // last A-iteration: preload V chunk 0 into Tb[0] (free: last reads hit Tb[1])
#pragma unroll
      for (int j = 0; j < 8; ++j) {
        dma16(vp[j], (void*)(Tb[0] + (w * 8 + j) * 1024));
        vp[j] += (size_t)64 * C_;
      }
    }
    const unsigned char* cbuf = Tb[c & 1];
#pragma unroll
    for (int kk2 = 0; kk2 < 2; ++kk2) {
      short8 aA = *(const short8*)(cbuf + (kk2 * 16 + (m0 >> 4)) * 1024 + frag_lane);
#pragma unroll
      for (int nt = 0; nt < 4; ++nt) {
        short8 bB = *(const short8*)(cbuf + (kk2 * 16 + w * 4 + nt) * 1024 + frag_lane);
        acc[nt] = mfma16(aA, bB, acc[nt]);
      }
    }
  }

  // ---- softmax epilogue: P -> LDS, ginv ----
  float rs[4] = {0.f, 0.f, 0.f, 0.f};
#pragma unroll
  for (int nt = 0; nt < 4; ++nt)
#pragma unroll
    for (int r = 0; r < 4; ++r) {
      float p = __expf(fmaf(acc[nt][r], scale, -SHIFT));
      rs[r] += p;
      Pl[(quad * 4 + r) * 264 + w * 64 + nt * 16 + l16] = f2bf(p);
    }
#pragma unroll
  for (int r = 0; r < 4; ++r)
#pragma unroll
    for (int off = 1; off < 16; off <<= 1) rs[r] += __shfl_xor(rs[r], off);
  if (l16 == 0) {
#pragma unroll
    for (int r = 0; r < 4; ++r) wsum[w][quad * 4 + r] = rs[r];
  }
  __syncthreads();
  if (tid < 16)
    ginvb[tid] = 1.0f / (wsum[0][tid] + wsum[1][tid] + wsum[2][tid] + wsum[3][tid]);
  __syncthreads();

  const float alpha = alpha_p[0], gamma = gamma_p[0];
  short8 Af[8];
#pragma unroll
  for (int ks = 0; ks < 8; ++ks)
    Af[ks] = *(const short8*)(&Pl[l16 * 264 + ks * 32 + quad * 8]);
  float gvr[4];
#pragma unroll
  for (int r = 0; r < 4; ++r) gvr[r] = alpha * ginvb[quad * 4 + r];

  // ---- Phase B: O = P@V over this L-half, 64-pos chunks double-buffered ----
  for (int cb = 0; cb < 16; ++cb) {
    BAR_FULL();
    if (cb < 15) {
      unsigned char* bp = Tb[(cb + 1) & 1];
#pragma unroll
      for (int j = 0; j < 8; ++j) {
        dma16(vp[j], (void*)(bp + (w * 8 + j) * 1024));
        vp[j] += (size_t)64 * C_;
      }
    }
    const unsigned char* vb = Tb[cb & 1];
    float4v f = (float4v){0.f, 0.f, 0.f, 0.f};
#pragma unroll
    for (int kk = 0; kk < 8; ++kk) {
      short8 bf = *(const short8*)(vb + (w * 8 + kk) * 1024 + frag_lane);
      f = mfma16(Af[kk], bf, f);
    }
    int col = Lh * 1024 + cb * 64 + w * 16 + l16;
#pragma unroll
    for (int r = 0; r < 4; ++r) {
      int row = m0 + quad * 4 + r;
      size_t idx = ((size_t)b * C_ + row) * L_ + col;
      out[idx] = fmaf(gvr[r], f[r], gamma * y[idx]);
    }
  }
}

// ---------------- time attention: out += beta*y_t (computed as O^T) --------
__global__ __launch_bounds__(256, 2) void time_kernel(
    const ushort* __restrict__ yb, const ushort* __restrict__ ytb,
    float* __restrict__ out, const float* __restrict__ beta_p) {
  const int blk = blockIdx.x;
  const int b = (blk & 7) + 8 * ((blk >> 3) & 1);
  const int m0 = (blk >> 4) * 64;
  const int tid = threadIdx.x;
  const int w = tid >> 6, lane = tid & 63, quad = lane >> 4, l16 = lane & 15;
  const int mtw = w >> 1, kt2 = w & 1;
  const float scale = 0.0625f;  // 1/sqrt(256)
  const float SHIFT = 16.0f;

  __shared__ __align__(16) unsigned char buf[2][32768];
  __shared__ ushort Pd[64 * 40];  // single buffer: BAR_FULL orders reads/writes
  __shared__ float wsum[4][64];
  __shared__ float ginv[64];

  const ushort* Yt = ytb + (size_t)b * L_ * C_;
  const ushort* Yb = yb + (size_t)b * C_ * L_;
  const int chq = ((lane & 3) - ((lane >> 3) & 3)) & 3;
  const int klK = (lane >> 2) * C_ + chq * 8;
  const int vlV = (lane >> 2) * L_ + chq * 8;
  const int sK = (quad + ((l16 >> 1) & 3)) & 3;
  const int frag_lane = l16 * 64 + sK * 16;

  // Q fragments
  short8 Qf[2][8];
#pragma unroll
  for (int mt = 0; mt < 2; ++mt)
#pragma unroll
    for (int kk = 0; kk < 8; ++kk)
      Qf[mt][kk] = *(const short8*)(Yt + (size_t)(m0 + mtw * 32 + mt * 16 + l16) * C_ +
                                    kk * 32 + quad * 8);

  // DMA pointers in registers, advanced by constant stride
  const ushort* dp[8];
#pragma unroll
  for (int j = 0; j < 8; ++j) {
    int gi = w * 8 + j;
    if (gi < 16) {
      int kk = gi >> 1, g = gi & 1;
      dp[j] = Yt + (size_t)(g * 16) * C_ + kk * 32 + klK;
    } else {
      int cg = gi - 16;
      dp[j] = Yb + (size_t)cg * 16 * L_ + vlV;
    }
  }
  const int dstride = (w < 2) ? 32 * C_ : 32;

  float4v facc[4][4];
#pragma unroll
  for (int mt = 0; mt < 4; ++mt)
#pragma unroll
    for (int nt = 0; nt < 4; ++nt) facc[mt][nt] = (float4v){0.f, 0.f, 0.f, 0.f};
  float rs[2][4] = {{0.f, 0.f, 0.f, 0.f}, {0.f, 0.f, 0.f, 0.f}};

  // preload chunk 0
#pragma unroll
  for (int j = 0; j < 8; ++j) {
    dma16(dp[j], (void*)(buf[0] + (w * 8 + j) * 1024));
    dp[j] += dstride;
  }

  for (int c = 0; c < 64; ++c) {
    const int cb = c & 1;
    BAR_FULL();  // DMA(c) landed; buf[cb^1] free; Pd reads of (c-1) done
    if (c < 63) {
      unsigned char* bp = buf[cb ^ 1];
#pragma unroll
      for (int j = 0; j < 8; ++j) {
        dma16(dp[j], (void*)(bp + (w * 8 + j) * 1024));
        dp[j] += dstride;
      }
    }
    // ---- QK: rows [mtw*32,+32) x keys [kt2*16,+16) ----
    float4v s0 = (float4v){0.f, 0.f, 0.f, 0.f};
    float4v s1 = (float4v){0.f, 0.f, 0.f, 0.f};
#pragma unroll
    for (int kk = 0; kk < 8; ++kk) {
      short8 bf = *(const short8*)(buf[cb] + (kk * 2 + kt2) * 1024 + frag_lane);
      s0 = mfma16(Qf[0][kk], bf, s0);
      s1 = mfma16(Qf[1][kk], bf, s1);
    }
#pragma unroll
    for (int mt = 0; mt < 2; ++mt) {
      float4v s = mt ? s1 : s0;
#pragma unroll
      for (int r = 0; r < 4; ++r) {
        float p = __expf(fmaf(s[r], scale, -SHIFT));
        rs[mt][r] += p;
        Pd[(mtw * 32 + mt * 16 + quad * 4 + r) * 40 + kt2 * 16 + l16] = f2bf(p);
      }
    }
    BAR_LGKM();  // P visible; DMA(c+1) stays in flight
    // ---- PV (O^T): ch [w*64,+64) x q [0,64) x K=32 ----
#pragma unroll
    for (int mt = 0; mt < 4; ++mt) {
      short8 va = *(const short8*)(buf[cb] + (16 + w * 4 + mt) * 1024 + frag_lane);
#pragma unroll
      for (int nt = 0; nt < 4; ++nt) {
        short8 pb = *(const short8*)(&Pd[(nt * 16 + l16) * 40 + quad * 8]);
        facc[mt][nt] = mfma16(va, pb, facc[mt][nt]);
      }
    }
  }

  // ---- normalization (per q column) ----
  __syncthreads();
#pragma unroll
  for (int mt = 0; mt < 2; ++mt)
#pragma unroll
    for (int r = 0; r < 4; ++r)
#pragma unroll
      for (int off = 1; off < 16; off <<= 1) rs[mt][r] += __shfl_xor(rs[mt][r], off);
  if (l16 == 0) {
#pragma unroll
    for (int mt = 0; mt < 2; ++mt)
#pragma unroll
      for (int r = 0; r < 4; ++r)
        wsum[w][mtw * 32 + mt * 16 + quad * 4 + r] = rs[mt][r];
  }
  __syncthreads();
  if (tid < 64) {
    int mh = tid >> 5;
    ginv[tid] = 1.0f / (wsum[mh * 2][tid] + wsum[mh * 2 + 1][tid]);
  }
  __syncthreads();

  const float beta = beta_p[0];
  float gq[4];
#pragma unroll
  for (int nt = 0; nt < 4; ++nt) gq[nt] = beta * ginv[nt * 16 + l16];

#pragma unroll
  for (int mt = 0; mt < 4; ++mt)
#pragma unroll
    for (int nt = 0; nt < 4; ++nt)
#pragma unroll
      for (int r = 0; r < 4; ++r) {
        int ch = w * 64 + mt * 16 + quad * 4 + r;
        size_t idx = ((size_t)b * C_ + ch) * L_ + m0 + nt * 16 + l16;
        out[idx] = fmaf(gq[nt], facc[mt][nt][r], out[idx]);
      }
}

extern "C" void kernel_launch(void* const* d_in, const int* in_sizes, int n_in,
                              void* d_out, int out_size, void* d_ws, size_t ws_size,
                              hipStream_t stream) {
  const float* y = (const float*)d_in[0];
  const float* alpha = (const float*)d_in[1];
  const float* beta = (const float*)d_in[2];
  const float* gamma = (const float*)d_in[3];
  float* out = (float*)d_out;

  ushort* yb = (ushort*)d_ws;                       // [B,C,L] bf16   16.8MB
  ushort* ytb = yb + (size_t)B_ * C_ * L_;          // [B,L,C] bf16   16.8MB

  hipLaunchKernelGGL(cvt_kernel, dim3(L_ / 32, C_ / 32, B_), dim3(256), 0, stream,
                     y, yb, ytb);
  hipLaunchKernelGGL(chan_kernel, dim3(512), dim3(256), 0, stream,
                     yb, ytb, y, out, alpha, gamma);
  hipLaunchKernelGGL(time_kernel, dim3(512), dim3(256), 0, stream,
                     yb, ytb, out, beta);
}